// Round 1
// baseline (199.354 us; speedup 1.0000x reference)
//
#include <hip/hip_runtime.h>

#define EPS 1e-12f

// MovingAvgNormNonBias: x [B=32, T=3000, D=512] fp32, kernel_size k (=100).
// Sliding window [t-k/2, t+k-k/2-1] sums via running accumulators; denom
// replicates the reference's torch-style ramp/flat/ramp construction.

__global__ __launch_bounds__(128) void mavn_kernel(
    const float* __restrict__ x, const int* __restrict__ kptr,
    float* __restrict__ out, int T, int D, int TCHUNK)
{
    const int k = kptr[0];
    const int half = k >> 1;           // k//2
    const int b = blockIdx.y;
    const int t0 = blockIdx.x * TCHUNK;
    if (t0 >= T) return;
    const int t1 = min(T, t0 + TCHUNK);
    const int d4 = threadIdx.x;        // 0..D/4-1
    const size_t base = ((size_t)b * T) * (size_t)D + (size_t)d4 * 4;
    const float* xp = x + base;
    float* op = out + base;

    float s1[4] = {0.f, 0.f, 0.f, 0.f};
    float s2[4] = {0.f, 0.f, 0.f, 0.f};

    // initial window for t0: rows [t0-half, t0+k-half-1] clipped to [0,T)
    const int wlo = t0 - half;
    const int whi = t0 + (k - half);   // exclusive
    for (int j = (wlo > 0 ? wlo : 0); j < (whi < T ? whi : T); ++j) {
        const float4 v = *(const float4*)(xp + (size_t)j * D);
        const float vv[4] = {v.x, v.y, v.z, v.w};
#pragma unroll
        for (int c = 0; c < 4; ++c) { s1[c] += vv[c]; s2[c] += vv[c] * vv[c]; }
    }

    const float kf = (float)k;
    const float inv_km1 = 1.0f / (float)(k - 1);
    const int tail_start = T - (k - half);   // = T - 50 for k=100

    for (int t = t0; t < t1; ++t) {
        if (t > t0) {
            const int ja = t + (k - half) - 1;   // incoming row t + 49
            if (ja < T) {
                const float4 v = *(const float4*)(xp + (size_t)ja * D);
                const float vv[4] = {v.x, v.y, v.z, v.w};
#pragma unroll
                for (int c = 0; c < 4; ++c) { s1[c] += vv[c]; s2[c] += vv[c] * vv[c]; }
            }
            const int jr = t - half - 1;         // outgoing row t - 51
            if (jr >= 0) {
                const float4 v = *(const float4*)(xp + (size_t)jr * D);
                const float vv[4] = {v.x, v.y, v.z, v.w};
#pragma unroll
                for (int c = 0; c < 4; ++c) { s1[c] -= vv[c]; s2[c] -= vv[c] * vv[c]; }
            }
        }
        // reference denom: ramp k//2..k-1, flat k, ramp k-1..k//2
        float denom;
        if (t < half)            denom = (float)(half + t);
        else if (t < tail_start) denom = kf;
        else                     denom = (float)((k - 1) - (t - tail_start));
        const float inv_denom = 1.0f / denom;

        const float4 xc4 = *(const float4*)(xp + (size_t)t * D);
        const float xc[4] = {xc4.x, xc4.y, xc4.z, xc4.w};
        float oo[4];
#pragma unroll
        for (int c = 0; c < 4; ++c) {
            const float m = s1[c] * inv_denom;
            float var_sum = s2[c] - 2.0f * m * s1[c] + kf * m * m;
            var_sum = fmaxf(var_sum, 0.0f);           // guard fp drift
            const float sd = sqrtf(var_sum * inv_km1);
            oo[c] = (xc[c] - m) / (sd + EPS);
        }
        float4 o; o.x = oo[0]; o.y = oo[1]; o.z = oo[2]; o.w = oo[3];
        *(float4*)(op + (size_t)t * D) = o;
    }
}

extern "C" void kernel_launch(void* const* d_in, const int* in_sizes, int n_in,
                              void* d_out, int out_size, void* d_ws, size_t ws_size,
                              hipStream_t stream) {
    const float* x = (const float*)d_in[0];
    const int* kptr = (const int*)d_in[1];
    float* out = (float*)d_out;

    const int B = 32, T = 3000, D = 512;   // from setup_inputs: x [32,3000,512]
    (void)in_sizes; (void)n_in; (void)d_ws; (void)ws_size; (void)out_size;

    const int TCHUNK = 100;
    const int nchunk = (T + TCHUNK - 1) / TCHUNK;   // 30
    dim3 grid(nchunk, B);
    dim3 block(D / 4);                               // 128 threads
    mavn_kernel<<<grid, block, 0, stream>>>(x, kptr, out, T, D, TCHUNK);
}

// Round 2
// 130.532 us; speedup vs baseline: 1.5272x; 1.5272x over previous
//
#include <hip/hip_runtime.h>

#define EPS 1e-12f

// MovingAvgNormNonBias: x [B=32, T=3000, D=512] fp32, kernel_size k (=100).
// Two-kernel scheme:
//   k1: 25-row segment sums (s1, s2) per (b, seg, d4-column) into d_ws.
//   k2: one block per (b, 25-row chunk); window init = 4 segment sums;
//       then streaming add/sub with running accumulators.
// XCD swizzle: consecutive slots on an XCD walk consecutive chunks of the
// same batch so halo/add/sub/numerator streams overlap in that XCD's L2.

constexpr int Bq = 32, Tq = 3000, Dq = 512;
constexpr int SEG = 25;
constexpr int NSEG = Tq / SEG;        // 120
constexpr int NCHUNK = Tq / SEG;      // 120 (chunk == segment length)
constexpr int NB = Bq * NCHUNK;       // 3840 blocks for k2
constexpr int NXCD = 8;

__global__ __launch_bounds__(128) void seg_sums_kernel(
    const float* __restrict__ x, float* __restrict__ ws)
{
    const int s = blockIdx.x;          // segment 0..NSEG-1
    const int b = blockIdx.y;
    const int d4 = threadIdx.x;        // 0..127
    const float* xp = x + ((size_t)b * Tq) * Dq + (size_t)d4 * 4;

    float s1[4] = {0.f, 0.f, 0.f, 0.f};
    float s2[4] = {0.f, 0.f, 0.f, 0.f};
    const int r0 = s * SEG;
    for (int j = 0; j < SEG; ++j) {
        const float4 v = *(const float4*)(xp + (size_t)(r0 + j) * Dq);
        const float vv[4] = {v.x, v.y, v.z, v.w};
#pragma unroll
        for (int c = 0; c < 4; ++c) { s1[c] += vv[c]; s2[c] += vv[c] * vv[c]; }
    }
    float4* w1 = (float4*)ws;                          // [B][NSEG][128]
    float4* w2 = w1 + (size_t)Bq * NSEG * (Dq / 4);
    const size_t idx = ((size_t)b * NSEG + s) * (Dq / 4) + d4;
    float4 o1; o1.x = s1[0]; o1.y = s1[1]; o1.z = s1[2]; o1.w = s1[3];
    float4 o2; o2.x = s2[0]; o2.y = s2[1]; o2.z = s2[2]; o2.w = s2[3];
    w1[idx] = o1; w2[idx] = o2;
}

__global__ __launch_bounds__(128) void mavn_kernel(
    const float* __restrict__ x, const int* __restrict__ kptr,
    float* __restrict__ out, const float* __restrict__ ws, int use_seg)
{
    // XCD-swizzled decode of (b, chunk)
    const int g = blockIdx.x;                  // 0..NB-1
    const int xcd = g & (NXCD - 1);
    const int slot = g >> 3;                   // 0..NB/8-1
    const int pair = xcd * (NB / NXCD) + slot;
    const int b = pair / NCHUNK;
    const int c = pair % NCHUNK;
    const int t0 = c * SEG;
    const int t1 = t0 + SEG;                   // Tq % SEG == 0

    const int k = kptr[0];
    const int half = k >> 1;
    const int d4 = threadIdx.x;
    const size_t base = ((size_t)b * Tq) * (size_t)Dq + (size_t)d4 * 4;
    const float* xp = x + base;
    float* op = out + base;

    float s1[4] = {0.f, 0.f, 0.f, 0.f};
    float s2[4] = {0.f, 0.f, 0.f, 0.f};

    if (use_seg && k == 4 * SEG) {
        // window for t0: rows [t0-50, t0+49] == segments c-2..c+1 (clipped)
        const float4* w1 = (const float4*)ws;
        const float4* w2 = w1 + (size_t)Bq * NSEG * (Dq / 4);
        const int slo = (c - 2 < 0) ? 0 : c - 2;
        const int shi = (c + 2 > NSEG) ? NSEG : c + 2;   // exclusive
        for (int s = slo; s < shi; ++s) {
            const size_t idx = ((size_t)b * NSEG + s) * (Dq / 4) + d4;
            const float4 a = w1[idx];
            const float4 q = w2[idx];
            s1[0] += a.x; s1[1] += a.y; s1[2] += a.z; s1[3] += a.w;
            s2[0] += q.x; s2[1] += q.y; s2[2] += q.z; s2[3] += q.w;
        }
    } else {
        // generic inline init: rows [t0-half, t0+k-half-1] clipped
        const int wlo = t0 - half;
        const int whi = t0 + (k - half);
        for (int j = (wlo > 0 ? wlo : 0); j < (whi < Tq ? whi : Tq); ++j) {
            const float4 v = *(const float4*)(xp + (size_t)j * Dq);
            const float vv[4] = {v.x, v.y, v.z, v.w};
#pragma unroll
            for (int cc = 0; cc < 4; ++cc) { s1[cc] += vv[cc]; s2[cc] += vv[cc] * vv[cc]; }
        }
    }

    const float kf = (float)k;
    const float inv_km1 = 1.0f / (float)(k - 1);
    const int tail_start = Tq - (k - half);

    for (int t = t0; t < t1; ++t) {
        if (t > t0) {
            const int ja = t + (k - half) - 1;   // incoming row
            if (ja < Tq) {
                const float4 v = *(const float4*)(xp + (size_t)ja * Dq);
                const float vv[4] = {v.x, v.y, v.z, v.w};
#pragma unroll
                for (int cc = 0; cc < 4; ++cc) { s1[cc] += vv[cc]; s2[cc] += vv[cc] * vv[cc]; }
            }
            const int jr = t - half - 1;         // outgoing row
            if (jr >= 0) {
                const float4 v = *(const float4*)(xp + (size_t)jr * Dq);
                const float vv[4] = {v.x, v.y, v.z, v.w};
#pragma unroll
                for (int cc = 0; cc < 4; ++cc) { s1[cc] -= vv[cc]; s2[cc] -= vv[cc] * vv[cc]; }
            }
        }
        float denom;
        if (t < half)            denom = (float)(half + t);
        else if (t < tail_start) denom = kf;
        else                     denom = (float)((k - 1) - (t - tail_start));
        const float inv_denom = 1.0f / denom;

        const float4 xc4 = *(const float4*)(xp + (size_t)t * Dq);
        const float xc[4] = {xc4.x, xc4.y, xc4.z, xc4.w};
        float oo[4];
#pragma unroll
        for (int cc = 0; cc < 4; ++cc) {
            const float m = s1[cc] * inv_denom;
            float var_sum = s2[cc] - 2.0f * m * s1[cc] + kf * m * m;
            var_sum = fmaxf(var_sum, 0.0f);
            const float sd = sqrtf(var_sum * inv_km1);
            oo[cc] = (xc[cc] - m) / (sd + EPS);
        }
        float4 o; o.x = oo[0]; o.y = oo[1]; o.z = oo[2]; o.w = oo[3];
        *(float4*)(op + (size_t)t * Dq) = o;
    }
}

extern "C" void kernel_launch(void* const* d_in, const int* in_sizes, int n_in,
                              void* d_out, int out_size, void* d_ws, size_t ws_size,
                              hipStream_t stream) {
    const float* x = (const float*)d_in[0];
    const int* kptr = (const int*)d_in[1];
    float* out = (float*)d_out;
    (void)in_sizes; (void)n_in; (void)out_size;

    const size_t ws_need = 2ull * Bq * NSEG * Dq * sizeof(float);  // 15.7 MB
    const int use_seg = (d_ws != nullptr && ws_size >= ws_need) ? 1 : 0;

    if (use_seg) {
        dim3 g1(NSEG, Bq);
        seg_sums_kernel<<<g1, 128, 0, stream>>>(x, (float*)d_ws);
    }
    mavn_kernel<<<NB, 128, 0, stream>>>(x, kptr, out, (const float*)d_ws, use_seg);
}

// Round 5
// 107.971 us; speedup vs baseline: 1.8464x; 1.2089x over previous
//
#include <hip/hip_runtime.h>

#define EPS 1e-12f

// MovingAvgNormNonBias: x [B=32, T=3000, D=512] fp32, kernel_size k (=100).
// k1: 25-row segment sums (s1, s2) per (b, seg, d4-column) into d_ws.
// k2: one block per (b, 25-row chunk); init = 4 segment sums; then a
//     software-pipelined streaming loop (prefetch t+1's in/out/num rows),
//     branchless denom, nontemporal output stores.
// XCD swizzle keeps chunks c-2..c+2 of one batch co-resident on one XCD so
// the 3x row reuse (incoming/numerator/outgoing) hits L2.

typedef float f4 __attribute__((ext_vector_type(4)));  // native vec: OK for __builtin_nontemporal_*

constexpr int Bq = 32, Tq = 3000, Dq = 512;
constexpr int SEG = 25;
constexpr int NSEG = Tq / SEG;        // 120
constexpr int NCHUNK = Tq / SEG;      // 120
constexpr int NB = Bq * NCHUNK;       // 3840 blocks for k2
constexpr int NXCD = 8;

__global__ __launch_bounds__(128) void seg_sums_kernel(
    const float* __restrict__ x, float* __restrict__ ws)
{
    const int s = blockIdx.x;          // segment 0..NSEG-1
    const int b = blockIdx.y;
    const int d4 = threadIdx.x;        // 0..127
    const float* xp = x + ((size_t)b * Tq) * Dq + (size_t)d4 * 4;

    f4 a1 = {0.f, 0.f, 0.f, 0.f};
    f4 a2 = a1, b1 = a1, b2 = a1;
    const int r0 = s * SEG;
#pragma unroll 5
    for (int j = 0; j < SEG; j += 2) {
        const f4 v = *(const f4*)(xp + (size_t)(r0 + j) * Dq);
        a1 += v; a2 += v * v;
        if (j + 1 < SEG) {
            const f4 w = *(const f4*)(xp + (size_t)(r0 + j + 1) * Dq);
            b1 += w; b2 += w * w;
        }
    }
    f4* w1 = (f4*)ws;                          // [B][NSEG][128]
    f4* w2 = w1 + (size_t)Bq * NSEG * (Dq / 4);
    const size_t idx = ((size_t)b * NSEG + s) * (Dq / 4) + d4;
    w1[idx] = a1 + b1;
    w2[idx] = a2 + b2;
}

__global__ __launch_bounds__(128) void mavn_kernel(
    const float* __restrict__ x, const int* __restrict__ kptr,
    float* __restrict__ out, const float* __restrict__ ws, int use_seg)
{
    // XCD-swizzled decode of (b, chunk)
    const int g = blockIdx.x;                  // 0..NB-1
    const int xcd = g & (NXCD - 1);
    const int slot = g >> 3;
    const int pair = xcd * (NB / NXCD) + slot;
    const int b = pair / NCHUNK;
    const int c = pair % NCHUNK;
    const int t0 = c * SEG;
    const int t1 = t0 + SEG;

    const int k = kptr[0];
    const int half = k >> 1;
    const int d4 = threadIdx.x;
    const size_t base = ((size_t)b * Tq) * (size_t)Dq + (size_t)d4 * 4;
    const float* xp = x + base;
    float* op = out + base;

    f4 s1 = {0.f, 0.f, 0.f, 0.f};
    f4 s2 = s1;

    if (use_seg && k == 4 * SEG) {
        // window for t0: rows [t0-50, t0+49] == segments c-2..c+1 (clipped)
        const f4* w1 = (const f4*)ws;
        const f4* w2 = w1 + (size_t)Bq * NSEG * (Dq / 4);
        const int slo = (c - 2 < 0) ? 0 : c - 2;
        const int shi = (c + 2 > NSEG) ? NSEG : c + 2;   // exclusive
        for (int s = slo; s < shi; ++s) {
            const size_t idx = ((size_t)b * NSEG + s) * (Dq / 4) + d4;
            s1 += w1[idx];
            s2 += w2[idx];
        }
    } else {
        // generic inline init: rows [t0-half, t0+k-half-1] clipped
        const int wlo = t0 - half;
        const int whi = t0 + (k - half);
        for (int j = (wlo > 0 ? wlo : 0); j < (whi < Tq ? whi : Tq); ++j) {
            const f4 v = *(const f4*)(xp + (size_t)j * Dq);
            s1 += v; s2 += v * v;
        }
    }

    const float kf = (float)k;
    const float inv_km1 = 1.0f / (float)(k - 1);
    const int tail_start = Tq - (k - half);

    // ---- software-pipelined streaming loop ----
    // State valid at loop top for iteration t:
    //   nx = x[t]; (ia, wa) = masked incoming row t+49; (ob, wb) = masked outgoing row t-51.
    // At t == t0 the add/sub masks are 0 (init already covers the window).
    f4 nx = *(const f4*)(xp + (size_t)t0 * Dq);
    f4 ia = {0.f, 0.f, 0.f, 0.f};
    f4 ob = ia;
    float wa = 0.f, wb = 0.f;

    for (int t = t0; t < t1; ++t) {
        const f4 cnum = nx;
        const f4 cin = ia;
        const f4 cout = ob;
        const float cwa = wa, cwb = wb;

        // prefetch for t+1 (unconditional clamped loads; masks kill edge rows)
        {
            const int tn = (t + 1 < t1) ? t + 1 : t;   // last iter: reload (harmless, L1-hot)
            nx = *(const f4*)(xp + (size_t)tn * Dq);
            int ja = tn + (k - half) - 1;
            int jr = tn - half - 1;
            wa = (ja < Tq && tn > t0) ? 1.f : 0.f;
            wb = (jr >= 0 && tn > t0) ? 1.f : 0.f;
            ja = ja < Tq - 1 ? ja : Tq - 1; ja = ja > 0 ? ja : 0;
            jr = jr > 0 ? jr : 0;
            ia = *(const f4*)(xp + (size_t)ja * Dq);
            ob = *(const f4*)(xp + (size_t)jr * Dq);
        }

        // window update (masked; no-op at t == t0)
        s1 += cwa * cin - cwb * cout;
        s2 += cwa * cin * cin - cwb * cout * cout;

        // branchless denom: ramp half..k-1, flat k, ramp k-1..half
        int idn = half + t;
        idn = idn < k ? idn : k;
        const int tail = (k - 1) - (t - tail_start);
        idn = idn < tail ? idn : tail;
        const float inv_denom = 1.0f / (float)idn;

        f4 o;
#pragma unroll
        for (int cc = 0; cc < 4; ++cc) {
            const float m = s1[cc] * inv_denom;
            float var_sum = s2[cc] - 2.0f * m * s1[cc] + kf * m * m;
            var_sum = fmaxf(var_sum, 0.0f);
            const float sd = sqrtf(var_sum * inv_km1);
            o[cc] = (cnum[cc] - m) / (sd + EPS);
        }
        __builtin_nontemporal_store(o, (f4*)(op + (size_t)t * Dq));
    }
}

extern "C" void kernel_launch(void* const* d_in, const int* in_sizes, int n_in,
                              void* d_out, int out_size, void* d_ws, size_t ws_size,
                              hipStream_t stream) {
    const float* x = (const float*)d_in[0];
    const int* kptr = (const int*)d_in[1];
    float* out = (float*)d_out;
    (void)in_sizes; (void)n_in; (void)out_size;

    const size_t ws_need = 2ull * Bq * NSEG * Dq * sizeof(float);  // 15.7 MB
    const int use_seg = (d_ws != nullptr && ws_size >= ws_need) ? 1 : 0;

    if (use_seg) {
        dim3 g1(NSEG, Bq);
        seg_sums_kernel<<<g1, 128, 0, stream>>>(x, (float*)d_ws);
    }
    mavn_kernel<<<NB, 128, 0, stream>>>(x, kptr, out, (const float*)d_ws, use_seg);
}

// Round 6
// 98.812 us; speedup vs baseline: 2.0175x; 1.0927x over previous
//
#include <hip/hip_runtime.h>

#define EPS 1e-12f

// MovingAvgNormNonBias: x [B=32, T=3000, D=512] fp32, kernel_size k (=100).
// k1: 25-row segment sums (s1, s2) per (b, seg, d4-column) into d_ws.
// k2: one block per (b, 25-row chunk); init = 4 segment sums; software-
//     pipelined streaming loop. Interior chunks (115/120) take an unmasked
//     fast path: denom==k, var = s2 - s1^2/k, rsqrt-based normalize.
// XCD swizzle keeps chunks c-2..c+2 of one batch co-resident on one XCD.

typedef float f4 __attribute__((ext_vector_type(4)));

constexpr int Bq = 32, Tq = 3000, Dq = 512;
constexpr int SEG = 25;
constexpr int NSEG = Tq / SEG;        // 120
constexpr int NCHUNK = Tq / SEG;      // 120
constexpr int NB = Bq * NCHUNK;       // 3840 blocks for k2
constexpr int NXCD = 8;

__global__ __launch_bounds__(128) void seg_sums_kernel(
    const float* __restrict__ x, float* __restrict__ ws)
{
    const int s = blockIdx.x;          // segment 0..NSEG-1
    const int b = blockIdx.y;
    const int d4 = threadIdx.x;        // 0..127
    const float* xp = x + ((size_t)b * Tq) * Dq + (size_t)d4 * 4;

    f4 a1 = {0.f, 0.f, 0.f, 0.f};
    f4 a2 = a1, b1 = a1, b2 = a1;
    const int r0 = s * SEG;
#pragma unroll 5
    for (int j = 0; j < SEG; j += 2) {
        const f4 v = *(const f4*)(xp + (size_t)(r0 + j) * Dq);
        a1 += v; a2 += v * v;
        if (j + 1 < SEG) {
            const f4 w = *(const f4*)(xp + (size_t)(r0 + j + 1) * Dq);
            b1 += w; b2 += w * w;
        }
    }
    f4* w1 = (f4*)ws;                          // [B][NSEG][128]
    f4* w2 = w1 + (size_t)Bq * NSEG * (Dq / 4);
    const size_t idx = ((size_t)b * NSEG + s) * (Dq / 4) + d4;
    w1[idx] = a1 + b1;
    w2[idx] = a2 + b2;
}

__global__ __launch_bounds__(128) void mavn_kernel(
    const float* __restrict__ x, const int* __restrict__ kptr,
    float* __restrict__ out, const float* __restrict__ ws, int use_seg)
{
    // XCD-swizzled decode of (b, chunk)
    const int g = blockIdx.x;                  // 0..NB-1
    const int xcd = g & (NXCD - 1);
    const int slot = g >> 3;
    const int pair = xcd * (NB / NXCD) + slot;
    const int b = pair / NCHUNK;
    const int c = pair % NCHUNK;
    const int t0 = c * SEG;
    const int t1 = t0 + SEG;

    const int k = kptr[0];
    const int half = k >> 1;
    const int d4 = threadIdx.x;
    const size_t base = ((size_t)b * Tq) * (size_t)Dq + (size_t)d4 * 4;
    const float* xp = x + base;
    float* op = out + base;

    f4 s1 = {0.f, 0.f, 0.f, 0.f};
    f4 s2 = s1;

    const bool seg_ok = use_seg && (k == 4 * SEG);

    if (seg_ok) {
        // window for t0: rows [t0-50, t0+49] == segments c-2..c+1 (clipped)
        const f4* w1 = (const f4*)ws;
        const f4* w2 = w1 + (size_t)Bq * NSEG * (Dq / 4);
        const int slo = (c - 2 < 0) ? 0 : c - 2;
        const int shi = (c + 2 > NSEG) ? NSEG : c + 2;   // exclusive
        for (int s = slo; s < shi; ++s) {
            const size_t idx = ((size_t)b * NSEG + s) * (Dq / 4) + d4;
            s1 += w1[idx];
            s2 += w2[idx];
        }
    } else {
        // generic inline init: rows [t0-half, t0+k-half-1] clipped
        const int wlo = t0 - half;
        const int whi = t0 + (k - half);
        for (int j = (wlo > 0 ? wlo : 0); j < (whi < Tq ? whi : Tq); ++j) {
            const f4 v = *(const f4*)(xp + (size_t)j * Dq);
            s1 += v; s2 += v * v;
        }
    }

    const float kf = (float)k;
    const float inv_km1 = 1.0f / (float)(k - 1);
    const int tail_start = Tq - (k - half);

    // interior: all window rows in-bounds AND denom == k for every t in chunk
    const bool interior = seg_ok && (t0 >= half) &&
                          (t0 + SEG + (k - half) - 1 <= Tq - 1) &&
                          (t0 + SEG - 1 < tail_start);

    if (interior) {
        const float inv_k = 1.0f / kf;
        // ---- peel j = 0: output from init sums ----
        {
            const f4 xc = *(const f4*)(xp + (size_t)t0 * Dq);
            f4 o;
#pragma unroll
            for (int cc = 0; cc < 4; ++cc) {
                const float m = s1[cc] * inv_k;
                float var_sum = s2[cc] - m * s1[cc];          // == s2 - s1^2/k
                var_sum = fmaxf(var_sum, 1e-12f);
                const float r = __builtin_amdgcn_rsqf(var_sum * inv_km1);
                o[cc] = (xc[cc] - m) * r;
            }
            __builtin_nontemporal_store(o, (f4*)(op + (size_t)t0 * Dq));
        }
        // ---- pipelined j = 1..SEG-1 ----
        f4 nx = *(const f4*)(xp + (size_t)(t0 + 1) * Dq);
        f4 ia = *(const f4*)(xp + (size_t)(t0 + (k - half)) * Dq);     // in for j=1
        f4 ob = *(const f4*)(xp + (size_t)(t0 - half) * Dq);           // out for j=1
        for (int j = 1; j < SEG; ++j) {
            const f4 cnum = nx;
            const f4 cin = ia;
            const f4 cob = ob;
            {
                const int jn = (j + 1 < SEG) ? j + 1 : j;    // last iter reloads (L1-hot)
                nx = *(const f4*)(xp + (size_t)(t0 + jn) * Dq);
                ia = *(const f4*)(xp + (size_t)(t0 + jn + (k - half) - 1) * Dq);
                ob = *(const f4*)(xp + (size_t)(t0 + jn - half - 1) * Dq);
            }
            s1 += cin - cob;
            s2 += cin * cin - cob * cob;
            f4 o;
#pragma unroll
            for (int cc = 0; cc < 4; ++cc) {
                const float m = s1[cc] * inv_k;
                float var_sum = s2[cc] - m * s1[cc];
                var_sum = fmaxf(var_sum, 1e-12f);
                const float r = __builtin_amdgcn_rsqf(var_sum * inv_km1);
                o[cc] = (cnum[cc] - m) * r;
            }
            __builtin_nontemporal_store(o, (f4*)(op + (size_t)(t0 + j) * Dq));
        }
        return;
    }

    // ---- general (edge) path: masked pipelined loop ----
    f4 nx = *(const f4*)(xp + (size_t)t0 * Dq);
    f4 ia = {0.f, 0.f, 0.f, 0.f};
    f4 ob = ia;
    float wa = 0.f, wb = 0.f;

    for (int t = t0; t < t1; ++t) {
        const f4 cnum = nx;
        const f4 cin = ia;
        const f4 cout = ob;
        const float cwa = wa, cwb = wb;

        {
            const int tn = (t + 1 < t1) ? t + 1 : t;
            nx = *(const f4*)(xp + (size_t)tn * Dq);
            int ja = tn + (k - half) - 1;
            int jr = tn - half - 1;
            wa = (ja < Tq && tn > t0) ? 1.f : 0.f;
            wb = (jr >= 0 && tn > t0) ? 1.f : 0.f;
            ja = ja < Tq - 1 ? ja : Tq - 1; ja = ja > 0 ? ja : 0;
            jr = jr > 0 ? jr : 0;
            ia = *(const f4*)(xp + (size_t)ja * Dq);
            ob = *(const f4*)(xp + (size_t)jr * Dq);
        }

        s1 += cwa * cin - cwb * cout;
        s2 += cwa * cin * cin - cwb * cout * cout;

        // branchless denom: ramp half..k-1, flat k, ramp k-1..half
        int idn = half + t;
        idn = idn < k ? idn : k;
        const int tail = (k - 1) - (t - tail_start);
        idn = idn < tail ? idn : tail;
        const float inv_denom = __builtin_amdgcn_rcpf((float)idn);

        f4 o;
#pragma unroll
        for (int cc = 0; cc < 4; ++cc) {
            const float m = s1[cc] * inv_denom;
            float var_sum = s2[cc] - 2.0f * m * s1[cc] + kf * m * m;
            var_sum = fmaxf(var_sum, 0.0f);
            const float sd = __builtin_amdgcn_sqrtf(var_sum * inv_km1);
            o[cc] = (cnum[cc] - m) * __builtin_amdgcn_rcpf(sd + EPS);
        }
        __builtin_nontemporal_store(o, (f4*)(op + (size_t)t * Dq));
    }
}

extern "C" void kernel_launch(void* const* d_in, const int* in_sizes, int n_in,
                              void* d_out, int out_size, void* d_ws, size_t ws_size,
                              hipStream_t stream) {
    const float* x = (const float*)d_in[0];
    const int* kptr = (const int*)d_in[1];
    float* out = (float*)d_out;
    (void)in_sizes; (void)n_in; (void)out_size;

    const size_t ws_need = 2ull * Bq * NSEG * Dq * sizeof(float);  // 15.7 MB
    const int use_seg = (d_ws != nullptr && ws_size >= ws_need) ? 1 : 0;

    if (use_seg) {
        dim3 g1(NSEG, Bq);
        seg_sums_kernel<<<g1, 128, 0, stream>>>(x, (float*)d_ws);
    }
    mavn_kernel<<<NB, 128, 0, stream>>>(x, kptr, out, (const float*)d_ws, use_seg);
}